// Round 5
// baseline (462.476 us; speedup 1.0000x reference)
//
#include <hip/hip_runtime.h>
#include <math.h>

#define Bn 16
#define Cn 3
#define Hn 512
#define Wn 512
#define HWn (Hn*Wn)          // 262144
#define CHWn (Cn*HWn)        // 786432
#define Rr 8                 // rows per thread strip

#define NB_MAIN (32*16*3)    // main-kernel grid size (blocks)

// ws layout (floats):
//   [0..4]   loss accumulators: con, gx, gy, cr, cb   (zeroed by kernel A)
//   [5]      arrival counter (as int)                  (zeroed by kernel A)
//   [8 + b*64 + sb]  gray partial sums, b=0..15, sb=0..63  (plain stores)

__device__ __forceinline__ float clamp01(float x) {
    return fminf(fmaxf(x, 0.0f), 1.0f);
}

// ---------------------------------------------------------------------------
// Kernel A: per-batch gray partial sums of input_ir (NO atomics, NO memset).
// grid = (64, B), block = 256. Block (sb,b) sums 4096 px -> ws[8 + b*64 + sb].
// Also zeroes the loss accumulators + counter (visible to B at kernel boundary).
// ---------------------------------------------------------------------------
__global__ __launch_bounds__(256) void gray_partial_kernel(
        const float* __restrict__ ir, float* __restrict__ ws)
{
    const int sb  = blockIdx.x;   // 0..63
    const int b   = blockIdx.y;   // 0..15
    const int tid = threadIdx.x;

    if (sb == 0 && b == 0) {
        if (tid < 5) ws[tid] = 0.0f;
        if (tid == 5) ((int*)ws)[5] = 0;
    }

    const float* base = ir + (size_t)b * CHWn;

    float sr = 0.f, sg = 0.f, sbm = 0.f;
#pragma unroll
    for (int k = 0; k < 4; ++k) {
        size_t px = (size_t)sb * 4096 + (size_t)(k * 256 + tid) * 4;
        float4 r4 = *(const float4*)(base + px);
        float4 g4 = *(const float4*)(base + HWn + px);
        float4 b4 = *(const float4*)(base + 2 * HWn + px);
        sr  += (r4.x + r4.y) + (r4.z + r4.w);
        sg  += (g4.x + g4.y) + (g4.z + g4.w);
        sbm += (b4.x + b4.y) + (b4.z + b4.w);
    }
    float s = 0.2989f * sr + 0.587f * sg + 0.114f * sbm;

#pragma unroll
    for (int off = 32; off; off >>= 1) s += __shfl_down(s, off, 64);

    __shared__ float red[4];
    if ((tid & 63) == 0) red[tid >> 6] = s;
    __syncthreads();
    if (tid == 0) ws[8 + b * 64 + sb] = (red[0] + red[1]) + (red[2] + red[3]);
}

// ---------------------------------------------------------------------------
// Kernel B: main fused kernel (R4 structure) + inline mean + last-block final.
// grid = (32, 16, 3) = 1536 blocks. Block z = channel c for sobel/intensity.
// Color pass: block z handles rows y of its strip with (y % 3) == z
// (even distribution -> no 1/3-block imbalance).
// Last block (arrival counter) computes the scalar loss -> d_out.
// ---------------------------------------------------------------------------
__global__ __launch_bounds__(256) void fusion_main_kernel(
        const float* __restrict__ vis, const float* __restrict__ ir,
        const float* __restrict__ outp, const float* __restrict__ mask,
        float* __restrict__ ws, float* __restrict__ dout)
{
    const int tid = threadIdx.x;
    const int tx = tid & 127;
    const int sy = tid >> 7;
    const int b  = blockIdx.y;
    const int c  = blockIdx.z;
    const int y0 = (blockIdx.x * 2 + sy) * Rr;
    const int x0 = tx * 4;

    // ---- batch mean of gray(ir): every wave gathers the 64 partials ----
    float p = ws[8 + b * 64 + (tid & 63)];
#pragma unroll
    for (int off = 32; off; off >>= 1) p += __shfl_down(p, off, 64);
    p = __shfl(p, 0, 64);                       // broadcast within wave
    const float moff = 0.8f * (p * (1.0f / (float)HWn));  // R_ir = clamp01(1.8*ir - moff)

    const size_t bb = (size_t)b * CHWn;
    const float* pv = vis  + bb;
    const float* pi = ir   + bb;
    const float* po = outp + bb;
    const float* pm = mask + bb;

    float conA = 0.f, gxA = 0.f, gyA = 0.f;

    // ---------------- sobel + intensity pass for channel c ----------------
    {
        const float* v_ = pv + (size_t)c * HWn;
        const float* i_ = pi + (size_t)c * HWn;
        const float* o_ = po + (size_t)c * HWn;
        const float* m_ = pm + (size_t)c * HWn;

        // sliding window: slot 0 = row y-1, 1 = row y, 2 = row y+1
        // 6 columns: x0-1 .. x0+4
        float wf[3][6], wv[3][6], wi[3][6];

        auto load_row = [&](int y, int s) {
            if ((unsigned)y < (unsigned)Hn) {
                size_t o = (size_t)y * Wn + x0;
                float4 o4 = *(const float4*)(o_ + o);
                float4 m4 = *(const float4*)(m_ + o);
                float4 v4 = *(const float4*)(v_ + o);
                float4 i4 = *(const float4*)(i_ + o);
                float oL = 0.f, mL = 0.f, vL = 0.f, iL = 0.f;
                float oR = 0.f, mR = 0.f, vR = 0.f, iR = 0.f;
                if (x0 > 0)      { oL = o_[o - 1]; mL = m_[o - 1]; vL = v_[o - 1]; iL = i_[o - 1]; }
                if (x0 + 4 < Wn) { oR = o_[o + 4]; mR = m_[o + 4]; vR = v_[o + 4]; iR = i_[o + 4]; }

                wf[s][0] = oL * mL;     wf[s][1] = o4.x * m4.x;
                wf[s][2] = o4.y * m4.y; wf[s][3] = o4.z * m4.z;
                wf[s][4] = o4.w * m4.w; wf[s][5] = oR * mR;

                // vis in [0,1) => sqrt in [0,1] => gamma clip is a no-op: drop it.
                wv[s][0] = sqrtf(vL);   wv[s][1] = sqrtf(v4.x);
                wv[s][2] = sqrtf(v4.y); wv[s][3] = sqrtf(v4.z);
                wv[s][4] = sqrtf(v4.w); wv[s][5] = sqrtf(vR);

                wi[s][0] = clamp01(fmaf(1.8f, iL,   -moff));
                wi[s][1] = clamp01(fmaf(1.8f, i4.x, -moff));
                wi[s][2] = clamp01(fmaf(1.8f, i4.y, -moff));
                wi[s][3] = clamp01(fmaf(1.8f, i4.z, -moff));
                wi[s][4] = clamp01(fmaf(1.8f, i4.w, -moff));
                wi[s][5] = clamp01(fmaf(1.8f, iR,   -moff));
                // OOB columns: source 0 -> derived value exactly 0, matching
                // the conv's zero padding of the derived planes.
                if (x0 == 0)       { wf[s][0] = 0.f; wv[s][0] = 0.f; wi[s][0] = 0.f; }
                if (x0 + 4 >= Wn)  { wf[s][5] = 0.f; wv[s][5] = 0.f; wi[s][5] = 0.f; }
            } else {
#pragma unroll
                for (int k = 0; k < 6; ++k) { wf[s][k] = 0.f; wv[s][k] = 0.f; wi[s][k] = 0.f; }
            }
        };

        load_row(y0 - 1, 0);
        load_row(y0,     1);

        for (int yy = 0; yy < Rr; ++yy) {
            load_row(y0 + yy + 1, 2);

#pragma unroll
            for (int j = 0; j < 4; ++j) {
                // cross-correlation (XLA conv): no kernel flip.
                float gxf = (wf[0][j+2] - wf[0][j]) + 2.f * (wf[1][j+2] - wf[1][j]) + (wf[2][j+2] - wf[2][j]);
                float gyf = (wf[0][j] + 2.f * wf[0][j+1] + wf[0][j+2]) - (wf[2][j] + 2.f * wf[2][j+1] + wf[2][j+2]);

                float gxv = (wv[0][j+2] - wv[0][j]) + 2.f * (wv[1][j+2] - wv[1][j]) + (wv[2][j+2] - wv[2][j]);
                float gyv = (wv[0][j] + 2.f * wv[0][j+1] + wv[0][j+2]) - (wv[2][j] + 2.f * wv[2][j+1] + wv[2][j+2]);

                float gxi = (wi[0][j+2] - wi[0][j]) + 2.f * (wi[1][j+2] - wi[1][j]) + (wi[2][j+2] - wi[2][j]);
                float gyi = (wi[0][j] + 2.f * wi[0][j+1] + wi[0][j+2]) - (wi[2][j] + 2.f * wi[2][j+1] + wi[2][j+2]);

                gxA  += fabsf(gxf - fmaxf(gxv, gxi));
                gyA  += fabsf(gyf - fmaxf(gyv, gyi));
                conA += fabsf(wf[1][j+1] - fmaxf(wv[1][j+1], wi[1][j+1]));
            }

#pragma unroll
            for (int k = 0; k < 6; ++k) {
                wf[0][k] = wf[1][k]; wf[1][k] = wf[2][k];
                wv[0][k] = wv[1][k]; wv[1][k] = wv[2][k];
                wi[0][k] = wi[1][k]; wi[1][k] = wi[2][k];
            }
        }
    }

    // ------- color pass: block z handles rows of its strip with y%3 == z -------
    float crA = 0.f, cbA = 0.f;
    {
        auto px = [&](float fr, float fg, float fb, float vr, float vg, float vb) {
            float fY = 0.299f * fr + 0.587f * fg + 0.114f * fb;
            float vY = 0.299f * vr + 0.587f * vg + 0.114f * vb;
            crA += fabsf((fr - fY) - (vr - vY)) * 0.713f;
            cbA += fabsf((fb - fY) - (vb - vY)) * 0.564f;
        };
        for (int y = y0; y < y0 + Rr; ++y) {
            if ((y % 3) != c) continue;          // wave-uniform condition
            size_t o = (size_t)y * Wn + x0;
            float4 oR = *(const float4*)(po + o);
            float4 oG = *(const float4*)(po + HWn + o);
            float4 oB = *(const float4*)(po + 2 * HWn + o);
            float4 mR = *(const float4*)(pm + o);
            float4 mG = *(const float4*)(pm + HWn + o);
            float4 mB = *(const float4*)(pm + 2 * HWn + o);
            float4 vR = *(const float4*)(pv + o);
            float4 vG = *(const float4*)(pv + HWn + o);
            float4 vB = *(const float4*)(pv + 2 * HWn + o);
            px(oR.x * mR.x, oG.x * mG.x, oB.x * mB.x,
               sqrtf(vR.x), sqrtf(vG.x), sqrtf(vB.x));
            px(oR.y * mR.y, oG.y * mG.y, oB.y * mB.y,
               sqrtf(vR.y), sqrtf(vG.y), sqrtf(vB.y));
            px(oR.z * mR.z, oG.z * mG.z, oB.z * mB.z,
               sqrtf(vR.z), sqrtf(vG.z), sqrtf(vB.z));
            px(oR.w * mR.w, oG.w * mG.w, oB.w * mB.w,
               sqrtf(vR.w), sqrtf(vG.w), sqrtf(vB.w));
        }
    }

    // ---------------- block reduction + atomics ----------------
    auto wred = [](float x) {
#pragma unroll
        for (int off = 32; off; off >>= 1) x += __shfl_down(x, off, 64);
        return x;
    };
    conA = wred(conA); gxA = wred(gxA); gyA = wred(gyA);
    crA  = wred(crA);  cbA = wred(cbA);

    __shared__ float red[5][4];
    __shared__ int is_last;
    const int lane = tid & 63, w = tid >> 6;
    if (lane == 0) {
        red[0][w] = conA; red[1][w] = gxA; red[2][w] = gyA;
        red[3][w] = crA;  red[4][w] = cbA;
    }
    __syncthreads();
    if (tid < 5) {
        float s = (red[tid][0] + red[tid][1]) + (red[tid][2] + red[tid][3]);
        atomicAdd(&ws[tid], s);
    }

    // ---------------- last-block finalization ----------------
    __threadfence();                 // accum atomics ordered before counter
    if (tid == 0) {
        int prev = atomicAdd((int*)ws + 5, 1);
        is_last = (prev == NB_MAIN - 1) ? 1 : 0;
    }
    __syncthreads();
    if (is_last && tid == 0) {
        // RMW reads at the coherent point -> current values
        float con = atomicAdd(&ws[0], 0.0f);
        float gx  = atomicAdd(&ws[1], 0.0f);
        float gy  = atomicAdd(&ws[2], 0.0f);
        float cr  = atomicAdd(&ws[3], 0.0f);
        float cb  = atomicAdd(&ws[4], 0.0f);
        const float invN3 = 1.0f / (float)((size_t)Bn * Cn * HWn);
        const float invN1 = 1.0f / (float)((size_t)Bn * HWn);
        dout[0] = 0.5f * (con * invN3)
                + 0.2f * (0.5f * (gx * invN3) + 0.5f * (gy * invN3))
                + (cb * invN1 + cr * invN1);
    }
}

extern "C" void kernel_launch(void* const* d_in, const int* in_sizes, int n_in,
                              void* d_out, int out_size, void* d_ws, size_t ws_size,
                              hipStream_t stream)
{
    const float* vis = (const float*)d_in[0];
    const float* ir  = (const float*)d_in[1];
    const float* out = (const float*)d_in[2];
    const float* msk = (const float*)d_in[3];
    float* ws = (float*)d_ws;

    gray_partial_kernel<<<dim3(64, Bn), 256, 0, stream>>>(ir, ws);
    fusion_main_kernel<<<dim3(Hn / (2 * Rr), Bn, Cn), 256, 0, stream>>>(
        vis, ir, out, msk, ws, (float*)d_out);
}

// Round 6
// 258.302 us; speedup vs baseline: 1.7904x; 1.7904x over previous
//
#include <hip/hip_runtime.h>
#include <math.h>

#define Bn 16
#define Cn 3
#define Hn 512
#define Wn 512
#define HWn (Hn*Wn)          // 262144
#define CHWn (Cn*HWn)        // 786432
#define Rr 4                 // rows per thread strip -> grid (64,16,3)=3072 blocks

// ws layout (floats):
//   [0..4]           loss accumulators: con, gx, gy, cr, cb (zeroed by gray kernel)
//   [8 + b*64 + sb]  gray partial sums, b=0..15, sb=0..63   (plain stores)

__device__ __forceinline__ float clamp01(float x) {
    return fminf(fmaxf(x, 0.0f), 1.0f);
}

// ---------------------------------------------------------------------------
// Kernel A: per-batch gray partial sums of input_ir (no atomics, no memset).
// grid = (64, B), block = 256. Block (sb,b) sums 4096 px -> ws[8 + b*64 + sb].
// Block (0,0) also zeroes the loss accumulators (kernel-boundary release
// makes them visible to kernel B).
// ---------------------------------------------------------------------------
__global__ __launch_bounds__(256) void gray_partial_kernel(
        const float* __restrict__ ir, float* __restrict__ ws)
{
    const int sb  = blockIdx.x;   // 0..63
    const int b   = blockIdx.y;   // 0..15
    const int tid = threadIdx.x;

    if (sb == 0 && b == 0 && tid < 5) ws[tid] = 0.0f;

    const float* base = ir + (size_t)b * CHWn;

    float sr = 0.f, sg = 0.f, sbm = 0.f;
#pragma unroll
    for (int k = 0; k < 4; ++k) {
        size_t px = (size_t)sb * 4096 + (size_t)(k * 256 + tid) * 4;
        float4 r4 = *(const float4*)(base + px);
        float4 g4 = *(const float4*)(base + HWn + px);
        float4 b4 = *(const float4*)(base + 2 * HWn + px);
        sr  += (r4.x + r4.y) + (r4.z + r4.w);
        sg  += (g4.x + g4.y) + (g4.z + g4.w);
        sbm += (b4.x + b4.y) + (b4.z + b4.w);
    }
    float s = 0.2989f * sr + 0.587f * sg + 0.114f * sbm;

#pragma unroll
    for (int off = 32; off; off >>= 1) s += __shfl_down(s, off, 64);

    __shared__ float red[4];
    if ((tid & 63) == 0) red[tid >> 6] = s;
    __syncthreads();
    if (tid == 0) ws[8 + b * 64 + sb] = (red[0] + red[1]) + (red[2] + red[3]);
}

// ---------------------------------------------------------------------------
// Kernel B: main fused kernel. grid = (Hn/(2*Rr), B, C) = (64,16,3) = 3072.
// Channel-split (z = channel); inline batch-mean gather; separable Sobel via
// column sums; static rotating window slots (no copy-down movs); color pass
// rows distributed evenly by y%3 == z. NO device-scope fences.
// ---------------------------------------------------------------------------
__global__ __launch_bounds__(256) void fusion_main_kernel(
        const float* __restrict__ vis, const float* __restrict__ ir,
        const float* __restrict__ outp, const float* __restrict__ mask,
        float* __restrict__ ws)
{
    const int tid = threadIdx.x;
    const int tx = tid & 127;
    const int sy = tid >> 7;
    const int b  = blockIdx.y;
    const int c  = blockIdx.z;
    const int y0 = (blockIdx.x * 2 + sy) * Rr;
    const int x0 = tx * 4;

    // ---- batch mean of gray(ir): wave gathers the 64 partials ----
    float p = ws[8 + b * 64 + (tid & 63)];
#pragma unroll
    for (int off = 32; off; off >>= 1) p += __shfl_down(p, off, 64);
    p = __shfl(p, 0, 64);
    const float moff = 0.8f * (p * (1.0f / (float)HWn));  // R_ir = clamp01(1.8*ir - moff)

    const size_t bb = (size_t)b * CHWn;
    const float* pv = vis  + bb;
    const float* pi = ir   + bb;
    const float* po = outp + bb;
    const float* pm = mask + bb;

    float conA = 0.f, gxA = 0.f, gyA = 0.f;

    // ---------------- sobel + intensity pass for channel c ----------------
    {
        const float* v_ = pv + (size_t)c * HWn;
        const float* i_ = pi + (size_t)c * HWn;
        const float* o_ = po + (size_t)c * HWn;
        const float* m_ = pm + (size_t)c * HWn;

        // rotating window slots (static, loop fully unrolled): 6 cols x0-1..x0+4
        float wf[3][6], wv[3][6], wi[3][6];

        auto load_row = [&](int y, int s) {
            if ((unsigned)y < (unsigned)Hn) {
                size_t o = (size_t)y * Wn + x0;
                float4 o4 = *(const float4*)(o_ + o);
                float4 m4 = *(const float4*)(m_ + o);
                float4 v4 = *(const float4*)(v_ + o);
                float4 i4 = *(const float4*)(i_ + o);
                float oL = 0.f, mL = 0.f, vL = 0.f, iL = 0.f;
                float oR = 0.f, mR = 0.f, vR = 0.f, iR = 0.f;
                if (x0 > 0)      { oL = o_[o - 1]; mL = m_[o - 1]; vL = v_[o - 1]; iL = i_[o - 1]; }
                if (x0 + 4 < Wn) { oR = o_[o + 4]; mR = m_[o + 4]; vR = v_[o + 4]; iR = i_[o + 4]; }

                wf[s][0] = oL * mL;     wf[s][1] = o4.x * m4.x;
                wf[s][2] = o4.y * m4.y; wf[s][3] = o4.z * m4.z;
                wf[s][4] = o4.w * m4.w; wf[s][5] = oR * mR;

                // vis in [0,1) => sqrt in [0,1] => gamma clip is a no-op.
                wv[s][0] = sqrtf(vL);   wv[s][1] = sqrtf(v4.x);
                wv[s][2] = sqrtf(v4.y); wv[s][3] = sqrtf(v4.z);
                wv[s][4] = sqrtf(v4.w); wv[s][5] = sqrtf(vR);

                wi[s][0] = clamp01(fmaf(1.8f, iL,   -moff));
                wi[s][1] = clamp01(fmaf(1.8f, i4.x, -moff));
                wi[s][2] = clamp01(fmaf(1.8f, i4.y, -moff));
                wi[s][3] = clamp01(fmaf(1.8f, i4.z, -moff));
                wi[s][4] = clamp01(fmaf(1.8f, i4.w, -moff));
                wi[s][5] = clamp01(fmaf(1.8f, iR,   -moff));
                // OOB columns: source 0 -> derived value exactly 0 (matches
                // the conv's zero padding of the derived planes).
                if (x0 == 0)       { wf[s][0] = 0.f; wv[s][0] = 0.f; wi[s][0] = 0.f; }
                if (x0 + 4 >= Wn)  { wf[s][5] = 0.f; wv[s][5] = 0.f; wi[s][5] = 0.f; }
            } else {
#pragma unroll
                for (int k = 0; k < 6; ++k) { wf[s][k] = 0.f; wv[s][k] = 0.f; wi[s][k] = 0.f; }
            }
        };

        load_row(y0 - 1, 0);
        load_row(y0,     1);

#pragma unroll
        for (int yy = 0; yy < Rr; ++yy) {
            const int st = yy % 3;          // row y-1
            const int sm = (yy + 1) % 3;    // row y
            const int sb2 = (yy + 2) % 3;   // row y+1
            load_row(y0 + yy + 1, sb2);

            // separable: t[k] = top + 2*mid + bot ; u[k] = top - bot
            float tf[6], uf[6], tv[6], uv[6], ti[6], ui[6];
#pragma unroll
            for (int k = 0; k < 6; ++k) {
                tf[k] = fmaf(2.f, wf[sm][k], wf[st][k] + wf[sb2][k]);
                uf[k] = wf[st][k] - wf[sb2][k];
                tv[k] = fmaf(2.f, wv[sm][k], wv[st][k] + wv[sb2][k]);
                uv[k] = wv[st][k] - wv[sb2][k];
                ti[k] = fmaf(2.f, wi[sm][k], wi[st][k] + wi[sb2][k]);
                ui[k] = wi[st][k] - wi[sb2][k];
            }
#pragma unroll
            for (int j = 0; j < 4; ++j) {
                float gxf = tf[j+2] - tf[j];
                float gyf = fmaf(2.f, uf[j+1], uf[j] + uf[j+2]);
                float gxv = tv[j+2] - tv[j];
                float gyv = fmaf(2.f, uv[j+1], uv[j] + uv[j+2]);
                float gxi = ti[j+2] - ti[j];
                float gyi = fmaf(2.f, ui[j+1], ui[j] + ui[j+2]);

                gxA  += fabsf(gxf - fmaxf(gxv, gxi));
                gyA  += fabsf(gyf - fmaxf(gyv, gyi));
                conA += fabsf(wf[sm][j+1] - fmaxf(wv[sm][j+1], wi[sm][j+1]));
            }
        }
    }

    // ------- color pass: block z handles rows of its strip with y%3 == z -------
    float crA = 0.f, cbA = 0.f;
    {
        auto px = [&](float fr, float fg, float fb, float vr, float vg, float vb) {
            float fY = 0.299f * fr + 0.587f * fg + 0.114f * fb;
            float vY = 0.299f * vr + 0.587f * vg + 0.114f * vb;
            crA += fabsf((fr - fY) - (vr - vY)) * 0.713f;
            cbA += fabsf((fb - fY) - (vb - vY)) * 0.564f;
        };
        for (int y = y0; y < y0 + Rr; ++y) {
            if ((y % 3) != c) continue;          // wave-uniform condition
            size_t o = (size_t)y * Wn + x0;
            float4 oR = *(const float4*)(po + o);
            float4 oG = *(const float4*)(po + HWn + o);
            float4 oB = *(const float4*)(po + 2 * HWn + o);
            float4 mR = *(const float4*)(pm + o);
            float4 mG = *(const float4*)(pm + HWn + o);
            float4 mB = *(const float4*)(pm + 2 * HWn + o);
            float4 vR = *(const float4*)(pv + o);
            float4 vG = *(const float4*)(pv + HWn + o);
            float4 vB = *(const float4*)(pv + 2 * HWn + o);
            px(oR.x * mR.x, oG.x * mG.x, oB.x * mB.x,
               sqrtf(vR.x), sqrtf(vG.x), sqrtf(vB.x));
            px(oR.y * mR.y, oG.y * mG.y, oB.y * mB.y,
               sqrtf(vR.y), sqrtf(vG.y), sqrtf(vB.y));
            px(oR.z * mR.z, oG.z * mG.z, oB.z * mB.z,
               sqrtf(vR.z), sqrtf(vG.z), sqrtf(vB.z));
            px(oR.w * mR.w, oG.w * mG.w, oB.w * mB.w,
               sqrtf(vR.w), sqrtf(vG.w), sqrtf(vB.w));
        }
    }

    // ---------------- block reduction + atomics ----------------
    auto wred = [](float x) {
#pragma unroll
        for (int off = 32; off; off >>= 1) x += __shfl_down(x, off, 64);
        return x;
    };
    conA = wred(conA); gxA = wred(gxA); gyA = wred(gyA);
    crA  = wred(crA);  cbA = wred(cbA);

    __shared__ float red[5][4];
    const int lane = tid & 63, w = tid >> 6;
    if (lane == 0) {
        red[0][w] = conA; red[1][w] = gxA; red[2][w] = gyA;
        red[3][w] = crA;  red[4][w] = cbA;
    }
    __syncthreads();
    if (tid < 5) {
        float s = (red[tid][0] + red[tid][1]) + (red[tid][2] + red[tid][3]);
        atomicAdd(&ws[tid], s);
    }
}

// ---------------------------------------------------------------------------
// Kernel C: finalize scalar loss (kernel boundary = visibility of ws[0..4]).
// loss = 0.5*con + 0.2*(0.5*gx + 0.5*gy) + (cb + cr)
// ---------------------------------------------------------------------------
__global__ void finalize_kernel(const float* __restrict__ ws, float* __restrict__ out)
{
    if (threadIdx.x == 0 && blockIdx.x == 0) {
        const float invN3 = 1.0f / (float)((size_t)Bn * Cn * HWn);
        const float invN1 = 1.0f / (float)((size_t)Bn * HWn);
        float con = ws[0] * invN3;
        float gx  = ws[1] * invN3;
        float gy  = ws[2] * invN3;
        float cr  = ws[3] * invN1;
        float cb  = ws[4] * invN1;
        out[0] = 0.5f * con + 0.2f * (0.5f * gx + 0.5f * gy) + (cb + cr);
    }
}

extern "C" void kernel_launch(void* const* d_in, const int* in_sizes, int n_in,
                              void* d_out, int out_size, void* d_ws, size_t ws_size,
                              hipStream_t stream)
{
    const float* vis = (const float*)d_in[0];
    const float* ir  = (const float*)d_in[1];
    const float* out = (const float*)d_in[2];
    const float* msk = (const float*)d_in[3];
    float* ws = (float*)d_ws;

    gray_partial_kernel<<<dim3(64, Bn), 256, 0, stream>>>(ir, ws);
    fusion_main_kernel<<<dim3(Hn / (2 * Rr), Bn, Cn), 256, 0, stream>>>(
        vis, ir, out, msk, ws);
    finalize_kernel<<<1, 64, 0, stream>>>(ws, (float*)d_out);
}